// Round 5
// baseline (99.785 us; speedup 1.0000x reference)
//
#include <hip/hip_runtime.h>
#include <math.h>

#define THREADS 256
#define BLOCKS  2048
#define STRIDE  (BLOCKS * THREADS)

__device__ __forceinline__ float wave_reduce(float v) {
    #pragma unroll
    for (int off = 32; off > 0; off >>= 1)
        v += __shfl_down(v, off, 64);
    return v;
}

__device__ __forceinline__ void accum_elem(float pp, float pt, float md, float tg,
                                           float V, float& phys, float& lm) {
    constexpr float P_ATM    = 0.101325f;
    constexpr float BETA     = 1466.96f;
    constexpr float INV_BETA = 1.0f / 1466.96f;
    constexpr float R_FRAC   = 0.005f / 0.995f;
    constexpr float C_RP     = R_FRAC * P_ATM;
    constexpr float RHO_MIX  = 851.6f + 1.225f * R_FRAC;
    constexpr float PT_EPS   = 1e-12f;

    float p_used  = fmaxf(pp * 0.1f, 1.0f);
    float inv_pu  = __builtin_amdgcn_rcpf(p_used);
    float p_denom = C_RP * inv_pu;
    float p_ratio = p_denom * inv_pu;
    float e       = __expf((P_ATM - p_used) * INV_BETA) * INV_BETA;
    float denom   = BETA * e + p_denom;
    float inv_d   = __builtin_amdgcn_rcpf(denom);
    float drho    = RHO_MIX * (e + p_ratio) * inv_d * inv_d;

    float res  = V * drho * pt - md;
    bool  m    = fabsf(pt) >= PT_EPS;
    phys += m ? fabsf(res)     : 0.0f;
    lm   += m ? fabsf(tg - pp) : 0.0f;
}

// Single kernel: streaming partial reduction, linear composition via
// device-scope float atomicAdd into d_out (zeroed by a memset graph node).
// No fences, no L2 flush, no ticket, no finisher kernel.
__global__ __launch_bounds__(THREADS) void loss_kernel(
    const float4* __restrict__ pp4,
    const float4* __restrict__ pt4,
    const float4* __restrict__ md4,
    const float4* __restrict__ tg4,
    const float*  __restrict__ Vp,
    const float*  __restrict__ logit,
    const float*  __restrict__ yf,
    int nb,
    float*        __restrict__ out,
    int n4, float inv_ns)
{
    const float V = Vp[0];
    float phys = 0.0f;
    float lm   = 0.0f;
    float cls  = 0.0f;

    const int tid = blockIdx.x * THREADS + threadIdx.x;

    // R1-style simple grid-stride loop (best measured variant).
    for (int i = tid; i < n4; i += STRIDE) {
        float4 a = pp4[i];
        float4 b = pt4[i];
        float4 c = md4[i];
        float4 d = tg4[i];
        const float* pa = (const float*)&a;
        const float* pb = (const float*)&b;
        const float* pc = (const float*)&c;
        const float* pd = (const float*)&d;
        #pragma unroll
        for (int j = 0; j < 4; ++j)
            accum_elem(pa[j], pb[j], pc[j], pd[j], V, phys, lm);
    }

    // Block 0 additionally computes the BCE term (512 elems over 256 threads).
    if (blockIdx.x == 0) {
        for (int i = threadIdx.x; i < nb; i += THREADS) {
            float x = logit[i];
            float y = yf[i];
            cls += fmaxf(x, 0.0f) - x * y + log1pf(__expf(-fabsf(x)));
        }
    }

    phys = wave_reduce(phys);
    lm   = wave_reduce(lm);
    cls  = wave_reduce(cls);

    __shared__ float sp[4], sl[4], sc[4];
    int lane = threadIdx.x & 63;
    int w    = threadIdx.x >> 6;
    if (lane == 0) { sp[w] = phys; sl[w] = lm; sc[w] = cls; }
    __syncthreads();
    if (threadIdx.x == 0) {
        float P = sp[0] + sp[1] + sp[2] + sp[3];
        float L = sl[0] + sl[1] + sl[2] + sl[3];

        // Linear composition: per-block contribution to each output.
        atomicAdd(&out[0], (L + 0.5f * P) * inv_ns);
        atomicAdd(&out[1], L * inv_ns);
        atomicAdd(&out[2], P * inv_ns);

        if (blockIdx.x == 0) {
            float C = sc[0] + sc[1] + sc[2] + sc[3];
            float loss_cls = C / (float)nb;
            atomicAdd(&out[0], 0.5f * loss_cls);
            atomicAdd(&out[3], loss_cls);
        }
    }
}

extern "C" void kernel_launch(void* const* d_in, const int* in_sizes, int n_in,
                              void* d_out, int out_size, void* d_ws, size_t ws_size,
                              hipStream_t stream) {
    const float* p_pred   = (const float*)d_in[0];
    const float* p_t_pred = (const float*)d_in[1];
    const float* logit    = (const float*)d_in[2];
    const float* yfault   = (const float*)d_in[3];
    const float* mdot_A   = (const float*)d_in[4];
    const float* tgt_p    = (const float*)d_in[5];
    const float* V        = (const float*)d_in[6];

    int n  = in_sizes[0];       // B*S = 8388608
    int nb = in_sizes[3];       // B = 512
    int n4 = n / 4;

    // Zero the 4 output floats each call (graph-capturable memset node).
    hipMemsetAsync(d_out, 0, 4 * sizeof(float), stream);

    loss_kernel<<<BLOCKS, THREADS, 0, stream>>>(
        (const float4*)p_pred, (const float4*)p_t_pred,
        (const float4*)mdot_A, (const float4*)tgt_p,
        V, logit, yfault, nb,
        (float*)d_out, n4, 1.0f / (float)n);
}

// Round 6
// 30.706 us; speedup vs baseline: 3.2497x; 3.2497x over previous
//
#include <hip/hip_runtime.h>
#include <math.h>

#define THREADS 256
#define BLOCKS  2048
#define STRIDE  (BLOCKS * THREADS)

__device__ __forceinline__ float wave_reduce(float v) {
    #pragma unroll
    for (int off = 32; off > 0; off >>= 1)
        v += __shfl_down(v, off, 64);
    return v;
}

__device__ __forceinline__ void accum_elem(float pp, float pt, float md, float tg,
                                           float V, float& phys, float& lm) {
    constexpr float P_ATM    = 0.101325f;
    constexpr float BETA     = 1466.96f;
    constexpr float INV_BETA = 1.0f / 1466.96f;
    constexpr float R_FRAC   = 0.005f / 0.995f;
    constexpr float C_RP     = R_FRAC * P_ATM;
    constexpr float RHO_MIX  = 851.6f + 1.225f * R_FRAC;
    constexpr float PT_EPS   = 1e-12f;

    float p_used  = fmaxf(pp * 0.1f, 1.0f);
    float inv_pu  = __builtin_amdgcn_rcpf(p_used);
    float p_denom = C_RP * inv_pu;
    float p_ratio = p_denom * inv_pu;
    float e       = __expf((P_ATM - p_used) * INV_BETA) * INV_BETA;
    float denom   = BETA * e + p_denom;
    float inv_d   = __builtin_amdgcn_rcpf(denom);
    float drho    = RHO_MIX * (e + p_ratio) * inv_d * inv_d;

    float res  = V * drho * pt - md;
    bool  m    = fabsf(pt) >= PT_EPS;
    phys += m ? fabsf(res)     : 0.0f;
    lm   += m ? fabsf(tg - pp) : 0.0f;
}

__device__ __forceinline__ void accum_vec4(const float4& a, const float4& b,
                                           const float4& c, const float4& d,
                                           float V, float& phys, float& lm) {
    accum_elem(a.x, b.x, c.x, d.x, V, phys, lm);
    accum_elem(a.y, b.y, c.y, d.y, V, phys, lm);
    accum_elem(a.z, b.z, c.z, d.z, V, phys, lm);
    accum_elem(a.w, b.w, c.w, d.w, V, phys, lm);
}

// ---------------- Kernel 1: main streaming reduction ----------------
__global__ __launch_bounds__(THREADS, 8) void loss_main_kernel(
    const float4* __restrict__ pp4,
    const float4* __restrict__ pt4,
    const float4* __restrict__ md4,
    const float4* __restrict__ tg4,
    const float*  __restrict__ Vp,
    float2*       __restrict__ partials,
    int n4)
{
    const float V = Vp[0];
    float phys = 0.0f;
    float lm   = 0.0f;

    const int tid = blockIdx.x * THREADS + threadIdx.x;

    int i = tid;
    // 2x-unrolled grid-stride: 8 independent float4 loads in flight,
    // named scalars only (no local arrays -> no alias-analysis load sinking).
    for (; i + STRIDE < n4; i += 2 * STRIDE) {
        float4 a0 = pp4[i];
        float4 b0 = pt4[i];
        float4 c0 = md4[i];
        float4 d0 = tg4[i];
        float4 a1 = pp4[i + STRIDE];
        float4 b1 = pt4[i + STRIDE];
        float4 c1 = md4[i + STRIDE];
        float4 d1 = tg4[i + STRIDE];
        accum_vec4(a0, b0, c0, d0, V, phys, lm);
        accum_vec4(a1, b1, c1, d1, V, phys, lm);
    }
    if (i < n4) {
        float4 a = pp4[i];
        float4 b = pt4[i];
        float4 c = md4[i];
        float4 d = tg4[i];
        accum_vec4(a, b, c, d, V, phys, lm);
    }

    phys = wave_reduce(phys);
    lm   = wave_reduce(lm);

    __shared__ float sp[4];
    __shared__ float sl[4];
    int lane = threadIdx.x & 63;
    int w    = threadIdx.x >> 6;
    if (lane == 0) { sp[w] = phys; sl[w] = lm; }
    __syncthreads();
    if (threadIdx.x == 0) {
        float P = sp[0] + sp[1] + sp[2] + sp[3];
        float L = sl[0] + sl[1] + sl[2] + sl[3];
        partials[blockIdx.x] = make_float2(P, L);
    }
}

// ---------------- Kernel 2: final reduce + BCE + compose ----------------
__global__ __launch_bounds__(THREADS) void loss_finish_kernel(
    const float2* __restrict__ partials, int nblk,
    const float*  __restrict__ logit,
    const float*  __restrict__ yf,
    int nb,
    float*        __restrict__ out,
    float inv_ns)
{
    float phys = 0.0f, lm = 0.0f, cls = 0.0f;

    for (int i = threadIdx.x; i < nblk; i += THREADS) {
        float2 p = partials[i];
        phys += p.x;
        lm   += p.y;
    }
    for (int i = threadIdx.x; i < nb; i += THREADS) {
        float x = logit[i];
        float y = yf[i];
        cls += fmaxf(x, 0.0f) - x * y + log1pf(__expf(-fabsf(x)));
    }

    phys = wave_reduce(phys);
    lm   = wave_reduce(lm);
    cls  = wave_reduce(cls);

    __shared__ float sp[4], sl[4], sc[4];
    int lane = threadIdx.x & 63;
    int w    = threadIdx.x >> 6;
    if (lane == 0) { sp[w] = phys; sl[w] = lm; sc[w] = cls; }
    __syncthreads();
    if (threadIdx.x == 0) {
        float P = sp[0] + sp[1] + sp[2] + sp[3];
        float L = sl[0] + sl[1] + sl[2] + sl[3];
        float C = sc[0] + sc[1] + sc[2] + sc[3];

        float loss_physics = P * inv_ns;
        float loss_M       = L * inv_ns;
        float loss_cls     = C / (float)nb;

        out[0] = loss_M + 0.5f * loss_physics + 0.5f * loss_cls;
        out[1] = loss_M;
        out[2] = loss_physics;
        out[3] = loss_cls;
    }
}

extern "C" void kernel_launch(void* const* d_in, const int* in_sizes, int n_in,
                              void* d_out, int out_size, void* d_ws, size_t ws_size,
                              hipStream_t stream) {
    const float* p_pred   = (const float*)d_in[0];
    const float* p_t_pred = (const float*)d_in[1];
    const float* logit    = (const float*)d_in[2];
    const float* yfault   = (const float*)d_in[3];
    const float* mdot_A   = (const float*)d_in[4];
    const float* tgt_p    = (const float*)d_in[5];
    const float* V        = (const float*)d_in[6];

    int n  = in_sizes[0];       // B*S = 8388608
    int nb = in_sizes[3];       // B = 512
    int n4 = n / 4;

    float2* partials = (float2*)d_ws;

    loss_main_kernel<<<BLOCKS, THREADS, 0, stream>>>(
        (const float4*)p_pred, (const float4*)p_t_pred,
        (const float4*)mdot_A, (const float4*)tgt_p,
        V, partials, n4);

    loss_finish_kernel<<<1, THREADS, 0, stream>>>(
        partials, BLOCKS, logit, yfault, nb,
        (float*)d_out, 1.0f / (float)n);
}

// Round 7
// 28.998 us; speedup vs baseline: 3.4411x; 1.0589x over previous
//
#include <hip/hip_runtime.h>
#include <math.h>

#define THREADS 256
#define BLOCKS  2048
#define STRIDE  (BLOCKS * THREADS)

__device__ __forceinline__ float wave_reduce(float v) {
    #pragma unroll
    for (int off = 32; off > 0; off >>= 1)
        v += __shfl_down(v, off, 64);
    return v;
}

__device__ __forceinline__ void accum_elem(float pp, float pt, float md, float tg,
                                           float V, float& phys, float& lm) {
    constexpr float P_ATM    = 0.101325f;
    constexpr float BETA     = 1466.96f;
    constexpr float INV_BETA = 1.0f / 1466.96f;
    constexpr float R_FRAC   = 0.005f / 0.995f;
    constexpr float C_RP     = R_FRAC * P_ATM;
    constexpr float RHO_MIX  = 851.6f + 1.225f * R_FRAC;
    constexpr float PT_EPS   = 1e-12f;

    float p_used  = fmaxf(pp * 0.1f, 1.0f);
    float inv_pu  = __builtin_amdgcn_rcpf(p_used);
    float p_denom = C_RP * inv_pu;
    float p_ratio = p_denom * inv_pu;
    float e       = __expf((P_ATM - p_used) * INV_BETA) * INV_BETA;
    float denom   = BETA * e + p_denom;
    float inv_d   = __builtin_amdgcn_rcpf(denom);
    float drho    = RHO_MIX * (e + p_ratio) * inv_d * inv_d;

    float res  = V * drho * pt - md;
    bool  m    = fabsf(pt) >= PT_EPS;
    phys += m ? fabsf(res)     : 0.0f;
    lm   += m ? fabsf(tg - pp) : 0.0f;
}

__device__ __forceinline__ void accum_vec4(const float4& a, const float4& b,
                                           const float4& c, const float4& d,
                                           float V, float& phys, float& lm) {
    accum_elem(a.x, b.x, c.x, d.x, V, phys, lm);
    accum_elem(a.y, b.y, c.y, d.y, V, phys, lm);
    accum_elem(a.z, b.z, c.z, d.z, V, phys, lm);
    accum_elem(a.w, b.w, c.w, d.w, V, phys, lm);
}

// ---------------- Kernel 1: main streaming reduction ----------------
// Software-pipelined: iteration i+1's loads are issued BEFORE iteration i's
// compute, so load issue is never stalled behind a waitcnt for current data.
__global__ __launch_bounds__(THREADS, 8) void loss_main_kernel(
    const float4* __restrict__ pp4,
    const float4* __restrict__ pt4,
    const float4* __restrict__ md4,
    const float4* __restrict__ tg4,
    const float*  __restrict__ Vp,
    float2*       __restrict__ partials,
    int n4)
{
    const float V = Vp[0];
    float phys = 0.0f;
    float lm   = 0.0f;

    const int tid = blockIdx.x * THREADS + threadIdx.x;

    if (tid < n4) {
        // prologue: first tile
        float4 a = pp4[tid];
        float4 b = pt4[tid];
        float4 c = md4[tid];
        float4 d = tg4[tid];

        int i = tid + STRIDE;
        for (; i < n4; i += STRIDE) {
            // issue next tile's loads (no dependency on current compute)
            float4 a2 = pp4[i];
            float4 b2 = pt4[i];
            float4 c2 = md4[i];
            float4 d2 = tg4[i];
            // compute current tile while next loads are in flight
            accum_vec4(a, b, c, d, V, phys, lm);
            a = a2; b = b2; c = c2; d = d2;
        }
        // epilogue
        accum_vec4(a, b, c, d, V, phys, lm);
    }

    phys = wave_reduce(phys);
    lm   = wave_reduce(lm);

    __shared__ float sp[4];
    __shared__ float sl[4];
    int lane = threadIdx.x & 63;
    int w    = threadIdx.x >> 6;
    if (lane == 0) { sp[w] = phys; sl[w] = lm; }
    __syncthreads();
    if (threadIdx.x == 0) {
        float P = sp[0] + sp[1] + sp[2] + sp[3];
        float L = sl[0] + sl[1] + sl[2] + sl[3];
        partials[blockIdx.x] = make_float2(P, L);
    }
}

// ---------------- Kernel 2: final reduce + BCE + compose ----------------
__global__ __launch_bounds__(THREADS) void loss_finish_kernel(
    const float4* __restrict__ partials4, int nblk4, // partials as float4 (2 blocks each)
    const float*  __restrict__ logit,
    const float*  __restrict__ yf,
    int nb,
    float*        __restrict__ out,
    float inv_ns)
{
    float phys = 0.0f, lm = 0.0f, cls = 0.0f;

    for (int i = threadIdx.x; i < nblk4; i += THREADS) {
        float4 p = partials4[i];     // (P0,L0,P1,L1)
        phys += p.x + p.z;
        lm   += p.y + p.w;
    }
    for (int i = threadIdx.x; i < nb; i += THREADS) {
        float x = logit[i];
        float y = yf[i];
        cls += fmaxf(x, 0.0f) - x * y + log1pf(__expf(-fabsf(x)));
    }

    phys = wave_reduce(phys);
    lm   = wave_reduce(lm);
    cls  = wave_reduce(cls);

    __shared__ float sp[4], sl[4], sc[4];
    int lane = threadIdx.x & 63;
    int w    = threadIdx.x >> 6;
    if (lane == 0) { sp[w] = phys; sl[w] = lm; sc[w] = cls; }
    __syncthreads();
    if (threadIdx.x == 0) {
        float P = sp[0] + sp[1] + sp[2] + sp[3];
        float L = sl[0] + sl[1] + sl[2] + sl[3];
        float C = sc[0] + sc[1] + sc[2] + sc[3];

        float loss_physics = P * inv_ns;
        float loss_M       = L * inv_ns;
        float loss_cls     = C / (float)nb;

        out[0] = loss_M + 0.5f * loss_physics + 0.5f * loss_cls;
        out[1] = loss_M;
        out[2] = loss_physics;
        out[3] = loss_cls;
    }
}

extern "C" void kernel_launch(void* const* d_in, const int* in_sizes, int n_in,
                              void* d_out, int out_size, void* d_ws, size_t ws_size,
                              hipStream_t stream) {
    const float* p_pred   = (const float*)d_in[0];
    const float* p_t_pred = (const float*)d_in[1];
    const float* logit    = (const float*)d_in[2];
    const float* yfault   = (const float*)d_in[3];
    const float* mdot_A   = (const float*)d_in[4];
    const float* tgt_p    = (const float*)d_in[5];
    const float* V        = (const float*)d_in[6];

    int n  = in_sizes[0];       // B*S = 8388608
    int nb = in_sizes[3];       // B = 512
    int n4 = n / 4;

    float2* partials = (float2*)d_ws;

    loss_main_kernel<<<BLOCKS, THREADS, 0, stream>>>(
        (const float4*)p_pred, (const float4*)p_t_pred,
        (const float4*)mdot_A, (const float4*)tgt_p,
        V, partials, n4);

    loss_finish_kernel<<<1, THREADS, 0, stream>>>(
        (const float4*)partials, BLOCKS / 2, logit, yfault, nb,
        (float*)d_out, 1.0f / (float)n);
}